// Round 1
// 831.520 us; speedup vs baseline: 1.0192x; 1.0192x over previous
//
#include <hip/hip_runtime.h>
#include <cstdint>

#define TOKENS 16384
#define IN_F   4096
#define OUT_F  4096

typedef int v4i __attribute__((ext_vector_type(4)));

// --- async global->LDS, 16B per lane (dest = wave-uniform base + lane*16) ---
__device__ __forceinline__ void async_lds16(const void* g, const void* l) {
    __builtin_amdgcn_global_load_lds(
        (const __attribute__((address_space(1))) void*)(uintptr_t)g,
        (__attribute__((address_space(3))) void*)(uint32_t)(uintptr_t)l,
        16, 0, 0);
}

// ---------------------------------------------------------------------------
// Kernel 1: per-token dynamic int8 quant of x. One block (256 thr) per row.
// ---------------------------------------------------------------------------
__global__ __launch_bounds__(256) void act_quant_kernel(
        const float* __restrict__ x,
        signed char* __restrict__ qx,
        float* __restrict__ act_scale) {
    const int row = blockIdx.x;
    const int tid = threadIdx.x;
    const float4* xr = (const float4*)(x + (size_t)row * IN_F);

    float4 v[4];
    float m = 0.f;
#pragma unroll
    for (int i = 0; i < 4; ++i) {
        v[i] = xr[i * 256 + tid];
        m = fmaxf(m, fmaxf(fmaxf(fabsf(v[i].x), fabsf(v[i].y)),
                           fmaxf(fabsf(v[i].z), fabsf(v[i].w))));
    }
#pragma unroll
    for (int off = 32; off > 0; off >>= 1)
        m = fmaxf(m, __shfl_xor(m, off, 64));
    __shared__ float wmax[4];
    if ((tid & 63) == 0) wmax[tid >> 6] = m;
    __syncthreads();
    m = fmaxf(fmaxf(wmax[0], wmax[1]), fmaxf(wmax[2], wmax[3]));

    const float inv = (m == 0.f) ? 0.f : 127.0f / m;
    if (tid == 0) act_scale[row] = (m == 0.f) ? 1.0f : m / 127.0f;

    int* qr = (int*)(qx + (size_t)row * IN_F);
#pragma unroll
    for (int i = 0; i < 4; ++i) {
        int q0 = (int)fminf(fmaxf(rintf(v[i].x * inv), -128.f), 127.f);
        int q1 = (int)fminf(fmaxf(rintf(v[i].y * inv), -128.f), 127.f);
        int q2 = (int)fminf(fmaxf(rintf(v[i].z * inv), -128.f), 127.f);
        int q3 = (int)fminf(fmaxf(rintf(v[i].w * inv), -128.f), 127.f);
        qr[i * 256 + tid] = (q0 & 255) | ((q1 & 255) << 8) |
                            ((q2 & 255) << 16) | ((q3 & 255) << 24);
    }
}

// ---------------------------------------------------------------------------
// Kernel 2: unpack int4 nibbles -> int8 [OUT_F][IN_F].
// ---------------------------------------------------------------------------
__global__ __launch_bounds__(256) void unpack_w_kernel(
        const int* __restrict__ qw,
        signed char* __restrict__ w8) {
    const size_t idx = ((size_t)blockIdx.x * 256 + threadIdx.x) * 4;
    const int4 q = *(const int4*)(qw + idx);
    const int b0 = ((((q.x >> 4) & 15) - 8) & 255);
    const int b1 = (((q.x & 15) - 8) & 255);
    const int b2 = ((((q.y >> 4) & 15) - 8) & 255);
    const int b3 = (((q.y & 15) - 8) & 255);
    const int b4 = ((((q.z >> 4) & 15) - 8) & 255);
    const int b5 = (((q.z & 15) - 8) & 255);
    const int b6 = ((((q.w >> 4) & 15) - 8) & 255);
    const int b7 = (((q.w & 15) - 8) & 255);
    int2 d;
    d.x = b0 | (b1 << 8) | (b2 << 16) | (b3 << 24);
    d.y = b4 | (b5 << 8) | (b6 << 16) | (b7 << 24);
    *(int2*)(w8 + idx * 2) = d;
}

// ---------------------------------------------------------------------------
// Kernel 3: int8 GEMM. BM=128, BN=256, BK=64. 256 thr = 4 waves (2x2),
// wave tile 64x128 = 4x8 grid of v_mfma_i32_16x16x64_i8.
//
// LDS layout is FRAGMENT-ORDER (zero bank conflicts, global_load_lds
// compatible), now DOUBLE-BUFFERED with a software pipeline:
//   prologue: stage tile 0 into buf0
//   iter t:   issue stage of tile t+1 into buf^1   (6 global_load_lds)
//             s_waitcnt vmcnt(6)  <- counted: waits ONLY tile t's 6 loads,
//                                    leaves tile t+1's 6 in flight
//             raw s_barrier       <- no compiler vmcnt(0)/lgkmcnt(0) drain
//             ds_read frags + 32 MFMA from buf
//             raw s_barrier       <- all waves done reading buf before it
//                                    gets overwritten next iteration
//   epilogue: peeled last tile with vmcnt(0)
// This removes the per-K-step full-latency serialization (the m97-class
// __syncthreads drain) that left MfmaUtil at 27%.
// ---------------------------------------------------------------------------
__global__ __launch_bounds__(256, 2) void gemm_i8_kernel(
        const signed char* __restrict__ qx,
        const signed char* __restrict__ w8,
        const float* __restrict__ act_scale,
        const float* __restrict__ wscale,
        const float* __restrict__ bias,
        float* __restrict__ out) {
    __shared__ __align__(16) signed char sA[2][128 * 64];   // 2 x 8 KiB
    __shared__ __align__(16) signed char sB[2][256 * 64];   // 2 x 16 KiB

    const int nt = blockIdx.x & 15;       // OUT_F/256 = 16 n-tiles
    const int mt = blockIdx.x >> 4;       // TOKENS/128 = 128 m-tiles
    const int m0 = mt * 128, n0 = nt * 256;
    const int tid  = threadIdx.x;
    const int lane = tid & 63;
    const int wave = tid >> 6;
    const int wm = (wave >> 1) * 64;      // wave row offset (0 or 64)
    const int wn = (wave & 1) * 128;      // wave col offset (0 or 128)

    // staging: wave w fills A-groups {2w,2w+1}, B-groups {4w..4w+3}.
    // lane's global element for group g: row = 16g + (lane&15), k = (lane>>4)*16
    const int lrow = lane & 15;
    const int lcol = (lane >> 4) * 16;
    const signed char* gA0 = qx + (size_t)(m0 + 16 * (2 * wave) + lrow) * IN_F + lcol;
    const signed char* gA1 = gA0 + 16 * IN_F;
    const signed char* gB0 = w8 + (size_t)(n0 + 16 * (4 * wave) + lrow) * IN_F + lcol;
    const signed char* gB1 = gB0 + 16 * IN_F;
    const signed char* gB2 = gB0 + 32 * IN_F;
    const signed char* gB3 = gB0 + 48 * IN_F;
    const int aoff = (2 * wave) * 1024;   // wave's A-group base within a buffer
    const int boff = (4 * wave) * 1024;   // wave's B-group base within a buffer

    v4i acc[4][8];
#pragma unroll
    for (int i = 0; i < 4; ++i)
#pragma unroll
        for (int j = 0; j < 8; ++j) acc[i][j] = (v4i){0, 0, 0, 0};

    auto STAGE = [&](int buf, int k0) {
        signed char* a = sA[buf] + aoff;
        signed char* b = sB[buf] + boff;
        async_lds16(gA0 + k0, a);
        async_lds16(gA1 + k0, a + 1024);
        async_lds16(gB0 + k0, b);
        async_lds16(gB1 + k0, b + 1024);
        async_lds16(gB2 + k0, b + 2048);
        async_lds16(gB3 + k0, b + 3072);
    };

    auto COMPUTE = [&](int buf) {
        const signed char* fA = sA[buf] + (wm >> 4) * 1024 + lane * 16;
        const signed char* fB = sB[buf] + (wn >> 4) * 1024 + lane * 16;
        v4i af[4], bf[8];
#pragma unroll
        for (int i = 0; i < 4; ++i)
            af[i] = *(const v4i*)(fA + i * 1024);
#pragma unroll
        for (int j = 0; j < 8; ++j)
            bf[j] = *(const v4i*)(fB + j * 1024);
#pragma unroll
        for (int i = 0; i < 4; ++i)
#pragma unroll
            for (int j = 0; j < 8; ++j)
                acc[i][j] = __builtin_amdgcn_mfma_i32_16x16x64_i8(
                    af[i], bf[j], acc[i][j], 0, 0, 0);
    };

    // ---- software pipeline ----
    STAGE(0, 0);
    int cur = 0;
    for (int k0 = 0; k0 < IN_F - 64; k0 += 64) {
        STAGE(cur ^ 1, k0 + 64);                       // next tile in flight
        asm volatile("s_waitcnt vmcnt(6)" ::: "memory"); // cur's 6 loads landed
        __builtin_amdgcn_s_barrier();                  // all waves' cur visible
        __builtin_amdgcn_sched_barrier(0);             // pin ds_reads after bar
        COMPUTE(cur);
        __builtin_amdgcn_sched_barrier(0);             // pin ds_reads before bar
        __builtin_amdgcn_s_barrier();                  // reads done -> safe to
        cur ^= 1;                                      //   overwrite next iter
    }
    asm volatile("s_waitcnt vmcnt(0)" ::: "memory");
    __builtin_amdgcn_s_barrier();
    __builtin_amdgcn_sched_barrier(0);
    COMPUTE(cur);

    // epilogue: out[m][n] = acc * act_scale[m]*wscale[n] + bias[n]
    // C/D mapping: col = lane&15, row = (lane>>4)*4 + reg
    const int col_lane = lane & 15;
    const int row_q    = (lane >> 4) * 4;
    float4 as4[4];
#pragma unroll
    for (int i = 0; i < 4; ++i)
        as4[i] = *(const float4*)(act_scale + m0 + wm + i * 16 + row_q);

#pragma unroll
    for (int j = 0; j < 8; ++j) {
        const int n = n0 + wn + j * 16 + col_lane;
        const float wsn = wscale[n];
        const float bn  = bias[n];
#pragma unroll
        for (int i = 0; i < 4; ++i) {
            const int mb = m0 + wm + i * 16 + row_q;
            float* orow = out + (size_t)mb * OUT_F + n;
            const float* asp = (const float*)&as4[i];
#pragma unroll
            for (int r = 0; r < 4; ++r)
                orow[(size_t)r * OUT_F] = (float)acc[i][j][r] * (asp[r] * wsn) + bn;
        }
    }
}

// ---------------------------------------------------------------------------
extern "C" void kernel_launch(void* const* d_in, const int* in_sizes, int n_in,
                              void* d_out, int out_size, void* d_ws, size_t ws_size,
                              hipStream_t stream) {
    const float* x    = (const float*)d_in[0];
    const int*   qw   = (const int*)d_in[1];
    const float* wsc  = (const float*)d_in[2];
    const float* bias = (const float*)d_in[3];
    float* out = (float*)d_out;

    char* ws = (char*)d_ws;
    float*       act_scale = (float*)ws;
    signed char* qx        = (signed char*)(ws + 65536);
    signed char* w8        = (signed char*)(ws + 65536 + (size_t)TOKENS * IN_F);

    act_quant_kernel<<<TOKENS, 256, 0, stream>>>(x, qx, act_scale);
    unpack_w_kernel<<<(OUT_F * (IN_F / 2) / 4) / 256, 256, 0, stream>>>(qw, w8);
    gemm_i8_kernel<<<(TOKENS / 128) * (OUT_F / 256), 256, 0, stream>>>(
        qx, w8, act_scale, wsc, bias, out);
}